// Round 4
// baseline (151.515 us; speedup 1.0000x reference)
//
#include <hip/hip_runtime.h>

// Network_49873160241834: fused LIF scan (B=256,F=10,C=3,T=8192) + conv(c) + linear(f).
//
// Speculative time-chunking: LIF resets v to EXACTLY 0 on every spike, and state
// error contracts by (1-k)<=0.8 per step, so a chunk warmed up from v=0 reaches the
// bit-exact true state with overwhelming probability (0.8^128 ~ 4e-13 << ulp, plus
// exact-0 spike sync ~every 2 steps; bench verifies). 32 chunks x (128 warm + 256
// main); each 64-thread block (1 wave) simulates TWO chunks (half 0 / half 1);
// grid (B,16) = 4096 one-wave blocks = 4 waves/SIMD.
//
// ROUND 4 theory: per-wave wall was ~9300 cyc/window vs ~900 cyc issue -> ~8.4k cyc
// of PRIVATE stall per window; 2->4 waves/SIMD gave only 4% -> stalls are private
// long-latency events, and VGPR_Count=44 (round 0) proves the small local arrays
// (gp[3]/lp[3]/adj[3], xs[4], previously bufA/bufB[8]) lived in SCRATCH = private
// GLOBAL memory (~700 cyc/access, rule #20). Fixes, all serving that theory:
//  1. ZERO local arrays: every pointer/offset/staged value is a named scalar.
//  2. ONE uniform loop body (no warmup/main if/else; only output stores guarded by
//     uniform w>=WWIN) -> no cross-BB liveness for MachineSink to spill.
//  3. 2-window staging pipeline, triple-buffered LDS (9.2 KB, 16 blocks/CU):
//     issue loads(w+2) -> sim(w) from LDS -> ds_write(w+1); compiler emits a
//     counted vmcnt(3) at the write -> ~2 windows of issue->wait distance.
// Kept: float4-granularity XOR swizzle (q ^ (row&7)) on both ds_write and ds_read;
// per-step x via ds_read_b128 with 2-quad software prefetch; __ballot spike capture
// (lane (o,tt) latches step-tt mask); LUT[6][2][32] conv+linear epilogue.
//
// EXACTNESS: v-update uses separately-rounded f32 ops (no FMA contraction) to match
// the f32 reference bit-exactly; chunk-0 staging pointers rewind WARM floats when
// the loads for window WWIN are issued, reproducing the original stream.

#define T_LEN 8192
#define NF 10
#define NSEQ 30
#define CHUNK 256
#define WARM 128
#define NCHUNKS 32          // T_LEN / CHUNK
#define NWIN 12             // (WARM + CHUNK) / 32 windows per chunk
#define WWIN 4              // warmup windows
#define NROW 20             // staged rows: 2 halves x 10 f
#define BUF4 (NROW * 8)     // float4s per window buffer (160)

__device__ __forceinline__ float lif_step(float xx, float v, float k, float vt, bool& s) {
  float d  = __fsub_rn(xx, v);   // rounded f32 sub
  float p  = __fmul_rn(k, d);    // rounded f32 mul (NOT fused)
  float vn = __fadd_rn(v, p);    // rounded f32 add
  s = vn > vt;                   // == (fl(vn - vt) > 0) in IEEE f32
  return s ? 0.0f : vn;          // exact reset to +0
}

__device__ __forceinline__ float lut_sum(unsigned m, const float* lut, int o, float bias) {
  float acc = bias;
#pragma unroll
  for (int g = 0; g < 6; ++g) {
    unsigned val = (m >> (5 * g)) & 31u;
    acc += lut[(g * 2 + o) * 32 + val];
  }
  return acc;
}

// one LIF step + ballot latch for step index T (compile-time literal)
#define STEP_CAP(XX, T)                                            \
  {                                                                \
    bool s;                                                        \
    v = lif_step((XX), v, k, vt, s);                               \
    unsigned long long ub = __ballot(s);                           \
    if (tt == (T)) {                                               \
      mA = (unsigned)(ub & 0xffffffffull);                         \
      mB = (unsigned)(ub >> 32);                                   \
    }                                                              \
  }

__global__ __launch_bounds__(64, 4) void lif_chunked(
    const float* __restrict__ x,      // (B, F, T)
    const float* __restrict__ tau,    // (3)
    const float* __restrict__ vth,    // (3)
    const float* __restrict__ convw,  // (3)
    const float* __restrict__ convb,  // (1)
    const float* __restrict__ linw,   // (2,10)
    const float* __restrict__ linb,   // (2)
    float* __restrict__ out)          // (B, 2, T)
{
  const int b    = blockIdx.x;
  const int cb   = blockIdx.y;       // 0..15, handles chunks 2cb, 2cb+1
  const int lane = threadIdx.x;
  const int half = lane >> 5;
  const int j    = lane & 31;
  const bool active = j < NSEQ;
  const int c = active ? j / NF : 0;
  const int f = active ? j % NF : 0;

  // LUT[g][o][val] = sum over set bits p of val of convw[(5g+p)/10]*linw[o,(5g+p)%10]
  __shared__ float lut[384];
  __shared__ float4 xbuf[3][BUF4];   // triple-buffered x window, XOR-swizzled
#pragma unroll
  for (int e = 0; e < 6; ++e) {
    int id = lane + 64 * e;
    int g = id >> 6, rem = id & 63, oo = rem >> 5, val = rem & 31;
    float sacc = 0.0f;
#pragma unroll
    for (int p = 0; p < 5; ++p) {
      if (val & (1 << p)) {
        int jj = 5 * g + p;
        sacc += convw[jj / NF] * linw[oo * NF + (jj % NF)];
      }
    }
    lut[id] = sacc;
  }
  __syncthreads();

  const float k  = __fmul_rn(0.001f, tau[c]);
  const float vt = active ? vth[c] : 3.0e38f;   // inactive lanes never spike
  const int chunk = cb * 2 + half;              // this lane's simulated chunk

  // sim-side LDS read: row = half*10 + f, swizzle key = row & 7
  const int srow = half * NF + f;
  const int sw   = srow & 7;

  // staging assignment: 160 (row,q) float4 slots; slot ids: lane (i0), lane+64 (i1),
  // (lane&31)+128 (i2, mirrored on both half-waves -> same addr, same data: benign).
  // ALL named scalars -- no arrays (scratch avoidance is the point of this round).
  const int id0 = lane,        id1 = lane + 64,  id2 = (lane & 31) + 128;
  const int row0 = id0 >> 3,   row1 = id1 >> 3,  row2 = id2 >> 3;
  const int q0 = id0 & 7,      q1 = id1 & 7,     q2 = id2 & 7;
  const int ch0 = 2 * cb + row0 / NF, ch1 = 2 * cb + row1 / NF, ch2 = 2 * cb + row2 / NF;
  const int fr0 = row0 % NF,   fr1 = row1 % NF,  fr2 = row2 % NF;
  const int ts0 = (ch0 == 0) ? 0 : ch0 * CHUNK - WARM;
  const int ts1 = (ch1 == 0) ? 0 : ch1 * CHUNK - WARM;
  const int ts2 = (ch2 == 0) ? 0 : ch2 * CHUNK - WARM;
  const float4* gp0 = (const float4*)(x + ((size_t)b * NF + fr0) * (size_t)T_LEN + ts0) + q0;
  const float4* gp1 = (const float4*)(x + ((size_t)b * NF + fr1) * (size_t)T_LEN + ts1) + q1;
  const float4* gp2 = (const float4*)(x + ((size_t)b * NF + fr2) * (size_t)T_LEN + ts2) + q2;
  const int lpo0 = row0 * 8 + (q0 ^ (row0 & 7));
  const int lpo1 = row1 * 8 + (q1 ^ (row1 & 7));
  const int lpo2 = row2 * 8 + (q2 ^ (row2 & 7));
  const int adj0 = (ch0 == 0) ? -(WARM / 4) : 0;   // chunk-0 rewind at window WWIN issue
  const int adj1 = (ch1 == 0) ? -(WARM / 4) : 0;
  const int adj2 = (ch2 == 0) ? -(WARM / 4) : 0;

  // epilogue role: lane = (o, tt)
  const int o  = half;
  const int tt = j;
  float wsum = 0.0f;
#pragma unroll
  for (int f2 = 0; f2 < NF; ++f2) wsum += linw[o * NF + f2];
  const float bias = linb[o] + convb[0] * wsum;

  const int tA = 2 * cb * CHUNK;             // half-0 chunk base time (block-uniform)
  float* outA = out + ((size_t)b * 2 + o) * T_LEN + tA;
  float* outB = outA + CHUNK;                // half-1 chunk base

  // ---- prologue: window 0 staged synchronously into buf 0; window 1 issued to regs
  float4 rA0 = gp0[0], rA1 = gp1[0], rA2 = gp2[0];
  gp0 += 8; gp1 += 8; gp2 += 8;
  {
    float4* wp = &xbuf[0][0];
    wp[lpo0] = rA0; wp[lpo1] = rA1; wp[lpo2] = rA2;
  }
  rA0 = gp0[0]; rA1 = gp1[0]; rA2 = gp2[0];   // window 1 in regs (written at w=0 tail)
  gp0 += 8; gp1 += 8; gp2 += 8;

  float v = 0.0f;

#pragma unroll 1
  for (int w = 0; w < NWIN; ++w) {
    // issue loads for window w+2 (kept in rB*, written to LDS next iteration)
    float4 rB0, rB1, rB2;
    const bool issueNext = (w + 2 < NWIN);
    if (issueNext) {
      if (w + 2 == WWIN) { gp0 += adj0; gp1 += adj1; gp2 += adj2; }
      rB0 = gp0[0]; rB1 = gp1[0]; rB2 = gp2[0];
      gp0 += 8; gp1 += 8; gp2 += 8;
    }

    // ---- sim 32 steps from buf[w%3] (uniform body; capture always on)
    const float4* rp = &xbuf[w % 3][srow * 8];
    unsigned mA = 0, mB = 0;
    float4 x0 = rp[0 ^ sw];
    float4 x1 = rp[1 ^ sw];
#pragma unroll
    for (int q = 0; q < 8; ++q) {
      float4 xn = x1;
      if (q + 2 < 8) xn = rp[(q + 2) ^ sw];
      STEP_CAP(x0.x, 4 * q + 0)
      STEP_CAP(x0.y, 4 * q + 1)
      STEP_CAP(x0.z, 4 * q + 2)
      STEP_CAP(x0.w, 4 * q + 3)
      x0 = x1; x1 = xn;
    }

    if (w >= WWIN) {   // main windows: fused conv+linear epilogue
      const int ow = w - WWIN;
      outA[ow * 32 + tt] = lut_sum(mA, lut, o, bias);
      outB[ow * 32 + tt] = lut_sum(mB, lut, o, bias);
    }
    if (w == WWIN - 1) v = (chunk == 0) ? 0.0f : v;  // chunk 0's true initial state

    // ---- write window w+1's staged regs to buf[(w+1)%3]
    // (compiler emits a counted vmcnt leaving rB* in flight -> ~2-window cover)
    if (w + 1 < NWIN) {
      float4* wp = &xbuf[(w + 1) % 3][0];
      wp[lpo0] = rA0; wp[lpo1] = rA1; wp[lpo2] = rA2;
    }
    rA0 = rB0; rA1 = rB1; rA2 = rB2;
  }
}

extern "C" void kernel_launch(void* const* d_in, const int* in_sizes, int n_in,
                              void* d_out, int out_size, void* d_ws, size_t ws_size,
                              hipStream_t stream) {
  const float* x     = (const float*)d_in[0];
  const float* tau   = (const float*)d_in[1];
  const float* vthp  = (const float*)d_in[2];
  const float* convw = (const float*)d_in[3];
  const float* convb = (const float*)d_in[4];
  const float* linw  = (const float*)d_in[5];
  const float* linb  = (const float*)d_in[6];
  float* out = (float*)d_out;

  const int B = in_sizes[0] / (NF * T_LEN);  // 256
  lif_chunked<<<dim3(B, NCHUNKS / 2), dim3(64), 0, stream>>>(
      x, tau, vthp, convw, convb, linw, linb, out);
}

// Round 10
// 146.483 us; speedup vs baseline: 1.0344x; 1.0344x over previous
//
#include <hip/hip_runtime.h>

// Network_49873160241834: fused LIF scan (B=256,F=10,C=3,T=8192) + conv(c) + linear(f).
//
// Speculative time-chunking: LIF resets v to EXACTLY 0 on every spike, and state
// error contracts by (1-k)<=0.8 per step, so a chunk warmed up from v=0 reaches the
// bit-exact true state with overwhelming probability (0.8^128 ~ 4e-13 << ulp, plus
// exact-0 spike sync ~every 2 steps; bench verifies). 32 chunks x (128 warm + 256
// main); each 64-thread block (1 wave) simulates TWO chunks (half 0 / half 1);
// grid (B,16) = 4096 one-wave blocks = 4 waves/SIMD.
//
// ROUND 10 = ROUND 8 resubmitted unchanged (rounds 8 AND 9 both died on container
// acquire -- broker outage; kernel has never run). R8 rationale: v_writelane
// inline-asm transport failed correctness twice (R6/R7) -> REVERTED to the
// R0-R4-proven C-level conditional latch. Evidence across all passing rounds shows
// per-SIMD step throughput invariant (~0.012 steps/cyc) vs staging method and
// occupancy, but PROPORTIONAL to instruction count -> the VALU pipe is saturated
// (VALUBusy ~52% is issue-slots; wave64 occupies the SIMD-32 pipe 2 cyc/instr ->
// ~104% true). So: cut per-step instructions, C-only:
//  1. 3-VALU latch: uM = (tt==T) ? ballot : uM on the full 64-bit mask (cmp-literal
//     + 2 cndmask-from-sgpr floor); half-split extracted ONCE per window.
//  2. Per-half epilogue partition (verified R7 logic): lane (h,tt) holds chunk-h's
//     step-tt mask and computes BOTH o outputs for chunk h (2 lut_sums + 2 stores).
//  3. 1-VALU/quad sim addressing: ds_read addr = wb ^ (q*16) -- exact identity
//     (srow*128 + ((srow&7)^q)*16), disjoint bit fields, no carries.
//  4. Warmup windows carry no capture at all (two-loop structure, R1/R3-proven).
// Kept: 2-buffer 1-ahead staging (issue loads(w+1) -> sim(w) -> ds_write(w+1));
// float4 XOR swizzle (q ^ (row&7)) on both sides; ds_read_b128 2-quad prefetch;
// named scalars only; LUT[6][2][32] conv+linear epilogue.
//
// EXACTNESS: v-update uses separately-rounded f32 ops (no FMA contraction) to match
// the f32 reference bit-exactly; chunk-0 staging pointers rewind WARM floats when
// the loads for window WWIN are issued, reproducing the original stream.

#define T_LEN 8192
#define NF 10
#define NSEQ 30
#define CHUNK 256
#define WARM 128
#define NCHUNKS 32          // T_LEN / CHUNK
#define NWIN 12             // (WARM + CHUNK) / 32 windows per chunk
#define WWIN 4              // warmup windows
#define NROW 20             // staged rows: 2 halves x 10 f
#define BUF4 (NROW * 8)     // float4s per window buffer (160)

__device__ __forceinline__ float lif_step(float xx, float v, float k, float vt, bool& s) {
  float d  = __fsub_rn(xx, v);   // rounded f32 sub
  float p  = __fmul_rn(k, d);    // rounded f32 mul (NOT fused)
  float vn = __fadd_rn(v, p);    // rounded f32 add
  s = vn > vt;                   // == (fl(vn - vt) > 0) in IEEE f32
  return s ? 0.0f : vn;          // exact reset to +0
}

__device__ __forceinline__ float lut_sum(unsigned m, const float* lut, int o, float bias) {
  float acc = bias;
#pragma unroll
  for (int g = 0; g < 6; ++g) {
    unsigned val = (m >> (5 * g)) & 31u;
    acc += lut[(g * 2 + o) * 32 + val];
  }
  return acc;
}

// one LIF step + capture: step T's full 64-bit ballot is conditionally latched by
// lane tt==T (v_cmp-literal + 2 cndmask floor; C-only, R0-proven construct class).
#define STEP_CAP(XX, T)                                \
  {                                                    \
    bool s;                                            \
    v = lif_step((XX), v, k, vt, s);                   \
    unsigned long long ub = __ballot(s);               \
    uM = (tt == (T)) ? ub : uM;                        \
  }

__global__ __launch_bounds__(64, 4) void lif_chunked(
    const float* __restrict__ x,      // (B, F, T)
    const float* __restrict__ tau,    // (3)
    const float* __restrict__ vth,    // (3)
    const float* __restrict__ convw,  // (3)
    const float* __restrict__ convb,  // (1)
    const float* __restrict__ linw,   // (2,10)
    const float* __restrict__ linb,   // (2)
    float* __restrict__ out)          // (B, 2, T)
{
  const int b    = blockIdx.x;
  const int cb   = blockIdx.y;       // 0..15, handles chunks 2cb, 2cb+1
  const int lane = threadIdx.x;
  const int half = lane >> 5;
  const int j    = lane & 31;
  const bool active = j < NSEQ;
  const int c = active ? j / NF : 0;
  const int f = active ? j % NF : 0;

  // LUT[g][o][val] = sum over set bits p of val of convw[(5g+p)/10]*linw[o,(5g+p)%10]
  __shared__ float lut[384];
  __shared__ float4 xbuf[2][BUF4];   // double-buffered x window, XOR-swizzled
#pragma unroll
  for (int e = 0; e < 6; ++e) {
    int id = lane + 64 * e;
    int g = id >> 6, rem = id & 63, oo = rem >> 5, val = rem & 31;
    float sacc = 0.0f;
#pragma unroll
    for (int p = 0; p < 5; ++p) {
      if (val & (1 << p)) {
        int jj = 5 * g + p;
        sacc += convw[jj / NF] * linw[oo * NF + (jj % NF)];
      }
    }
    lut[id] = sacc;
  }
  __syncthreads();

  const float k  = __fmul_rn(0.001f, tau[c]);
  const float vt = active ? vth[c] : 3.0e38f;   // inactive lanes never spike
  const int chunk = cb * 2 + half;              // this lane's simulated chunk

  // sim-side LDS read: row = half*10 + f; byte base folds the swizzle key so the
  // per-quad address is ONE v_xor with a literal: addr = wb ^ (q*16).
  const int srow  = half * NF + f;
  const char* sbase = (const char*)&xbuf[0][0];
  const int rbyte = srow * 128 + (srow & 7) * 16;   // bits>=7 | swizzle field bits 4..6

  // staging assignment: 160 (row,q) float4 slots; slot ids: lane (i0), lane+64 (i1),
  // (lane&31)+128 (i2, mirrored on both half-waves -> same addr, same data: benign).
  // ALL named scalars -- no local arrays (rule #20).
  const int id0 = lane,        id1 = lane + 64,  id2 = (lane & 31) + 128;
  const int row0 = id0 >> 3,   row1 = id1 >> 3,  row2 = id2 >> 3;
  const int q0 = id0 & 7,      q1 = id1 & 7,     q2 = id2 & 7;
  const int ch0 = 2 * cb + row0 / NF, ch1 = 2 * cb + row1 / NF, ch2 = 2 * cb + row2 / NF;
  const int fr0 = row0 % NF,   fr1 = row1 % NF,  fr2 = row2 % NF;
  const int ts0 = (ch0 == 0) ? 0 : ch0 * CHUNK - WARM;
  const int ts1 = (ch1 == 0) ? 0 : ch1 * CHUNK - WARM;
  const int ts2 = (ch2 == 0) ? 0 : ch2 * CHUNK - WARM;
  const float4* gp0 = (const float4*)(x + ((size_t)b * NF + fr0) * (size_t)T_LEN + ts0) + q0;
  const float4* gp1 = (const float4*)(x + ((size_t)b * NF + fr1) * (size_t)T_LEN + ts1) + q1;
  const float4* gp2 = (const float4*)(x + ((size_t)b * NF + fr2) * (size_t)T_LEN + ts2) + q2;
  const int lpo0 = row0 * 8 + (q0 ^ (row0 & 7));
  const int lpo1 = row1 * 8 + (q1 ^ (row1 & 7));
  const int lpo2 = row2 * 8 + (q2 ^ (row2 & 7));
  const int adj0 = (ch0 == 0) ? -(WARM / 4) : 0;   // chunk-0 rewind at window WWIN issue
  const int adj1 = (ch1 == 0) ? -(WARM / 4) : 0;
  const int adj2 = (ch2 == 0) ? -(WARM / 4) : 0;

  // epilogue role: lane (half, tt) handles BOTH o outputs of chunk `chunk` at
  // window-step tt (its own half of the latched 64-bit mask -- no cross-half ops).
  const int tt = j;
  float wsum0 = 0.0f, wsum1 = 0.0f;
#pragma unroll
  for (int f2 = 0; f2 < NF; ++f2) { wsum0 += linw[f2]; wsum1 += linw[NF + f2]; }
  const float bias0 = linb[0] + convb[0] * wsum0;
  const float bias1 = linb[1] + convb[0] * wsum1;

  const int tH = chunk * CHUNK;              // this half's chunk base time
  float* out0 = out + ((size_t)b * 2 + 0) * T_LEN + tH;
  float* out1 = out + ((size_t)b * 2 + 1) * T_LEN + tH;

  // ---- prologue: window 0 staged synchronously into buf 0
  {
    float4 s0 = gp0[0], s1 = gp1[0], s2 = gp2[0];
    gp0 += 8; gp1 += 8; gp2 += 8;
    float4* wp = &xbuf[0][0];
    wp[lpo0] = s0; wp[lpo1] = s1; wp[lpo2] = s2;
  }

  float v = 0.0f;

  // ---- warmup: no capture (R1/R3-proven structure)
#pragma unroll 1
  for (int w = 0; w < WWIN; ++w) {
    if (w + 1 == WWIN) { gp0 += adj0; gp1 += adj1; gp2 += adj2; }
    float4 rN0 = gp0[0], rN1 = gp1[0], rN2 = gp2[0];
    gp0 += 8; gp1 += 8; gp2 += 8;

    const int wb = rbyte + (w & 1) * (BUF4 * 16);
    float4 x0 = *(const float4*)(sbase + (wb ^ 0));
    float4 x1 = *(const float4*)(sbase + (wb ^ 16));
#pragma unroll
    for (int q = 0; q < 8; ++q) {
      float4 xn = x1;
      if (q + 2 < 8) xn = *(const float4*)(sbase + (wb ^ ((q + 2) << 4)));
      bool s;
      v = lif_step(x0.x, v, k, vt, s);
      v = lif_step(x0.y, v, k, vt, s);
      v = lif_step(x0.z, v, k, vt, s);
      v = lif_step(x0.w, v, k, vt, s);
      x0 = x1; x1 = xn;
    }

    float4* wp = &xbuf[(w + 1) & 1][0];
    wp[lpo0] = rN0; wp[lpo1] = rN1; wp[lpo2] = rN2;
  }
  v = (chunk == 0) ? 0.0f : v;   // chunk 0's true initial state

  // ---- main: capture + fused conv+linear epilogue
#pragma unroll 1
  for (int w = WWIN; w < NWIN; ++w) {
    float4 rN0, rN1, rN2;
    const bool haveNext = (w + 1 < NWIN);
    if (haveNext) {
      rN0 = gp0[0]; rN1 = gp1[0]; rN2 = gp2[0];
      gp0 += 8; gp1 += 8; gp2 += 8;
    }

    unsigned long long uM = 0;   // lane tt latches step-tt's full 64-bit ballot
    const int wb = rbyte + (w & 1) * (BUF4 * 16);
    float4 x0 = *(const float4*)(sbase + (wb ^ 0));
    float4 x1 = *(const float4*)(sbase + (wb ^ 16));
#pragma unroll
    for (int q = 0; q < 8; ++q) {
      float4 xn = x1;
      if (q + 2 < 8) xn = *(const float4*)(sbase + (wb ^ ((q + 2) << 4)));
      STEP_CAP(x0.x, 4 * q + 0)
      STEP_CAP(x0.y, 4 * q + 1)
      STEP_CAP(x0.z, 4 * q + 2)
      STEP_CAP(x0.w, 4 * q + 3)
      x0 = x1; x1 = xn;
    }

    // half-split once per window: chunk-h lanes take half h of the latched mask
    const unsigned vM = half ? (unsigned)(uM >> 32) : (unsigned)uM;
    const int ow = w - WWIN;
    out0[ow * 32 + tt] = lut_sum(vM, lut, 0, bias0);
    out1[ow * 32 + tt] = lut_sum(vM, lut, 1, bias1);

    if (haveNext) {
      float4* wp = &xbuf[(w + 1) & 1][0];
      wp[lpo0] = rN0; wp[lpo1] = rN1; wp[lpo2] = rN2;
    }
  }
}

extern "C" void kernel_launch(void* const* d_in, const int* in_sizes, int n_in,
                              void* d_out, int out_size, void* d_ws, size_t ws_size,
                              hipStream_t stream) {
  const float* x     = (const float*)d_in[0];
  const float* tau   = (const float*)d_in[1];
  const float* vthp  = (const float*)d_in[2];
  const float* convw = (const float*)d_in[3];
  const float* convb = (const float*)d_in[4];
  const float* linw  = (const float*)d_in[5];
  const float* linb  = (const float*)d_in[6];
  float* out = (float*)d_out;

  const int B = in_sizes[0] / (NF * T_LEN);  // 256
  lif_chunked<<<dim3(B, NCHUNKS / 2), dim3(64), 0, stream>>>(
      x, tau, vthp, convw, convb, linw, linb, out);
}